// Round 1
// baseline (873.316 us; speedup 1.0000x reference)
//
#include <hip/hip_runtime.h>

#define NPTS 100000
#define CC   64
#define KK   27
#define TOT  (KK * NPTS)        // 2,700,000 edges
#define SEGS (NPTS * KK)        // 2,700,000 (dst,k) segments
#define EPSBN 1e-5f
#define MT   128                // output rows per conv block
#define APAD 72                 // padded LDS row stride in bf16 elems (144B)

typedef float          f32x4  __attribute__((ext_vector_type(4)));
typedef short          bf16x8 __attribute__((ext_vector_type(8)));
typedef unsigned int   u32x4  __attribute__((ext_vector_type(4)));
typedef unsigned short u16x4  __attribute__((ext_vector_type(4)));

__device__ __forceinline__ float bf2f(unsigned short h) {
    return __uint_as_float(((unsigned int)h) << 16);
}
__device__ __forceinline__ unsigned short f2bf(float f) {
    unsigned int u = __float_as_uint(f);
    u = (u + 0x7fffu + ((u >> 16) & 1u)) >> 16;
    return (unsigned short)u;
}

// ---------------- prep: x -> bf16 ----------------
__global__ void k_convert_x(const float* __restrict__ x, unsigned short* __restrict__ xb) {
    int id = blockIdx.x * 256 + threadIdx.x;          // 1.6M threads, 4 elems each
    f32x4 v = ((const f32x4*)x)[id];
    u16x4 o;
#pragma unroll
    for (int j = 0; j < 4; ++j) o[j] = f2bf(v[j]);
    ((u16x4*)xb)[id] = o;
}

// ---------------- prep: W[k][cin][cout] fp32 -> Wt[k][cout][cin] bf16 (both layers) ---
__global__ void k_prep_w(const float* __restrict__ W1, const float* __restrict__ W2,
                         unsigned short* __restrict__ Wt1, unsigned short* __restrict__ Wt2) {
    int id = blockIdx.x * 256 + threadIdx.x;          // 2*27*4096 threads
    int which = id / (KK * CC * CC);
    int r = id % (KK * CC * CC);
    int k = r / (CC * CC);
    int rem = r % (CC * CC);
    int cin = rem / CC, cout = rem % CC;
    const float* W = which ? W2 : W1;
    unsigned short* Wt = which ? Wt2 : Wt1;
    Wt[k * CC * CC + cout * CC + cin] = f2bf(W[r]);
}

// ---------------- CSR build ----------------
__global__ void k_hist(const int* __restrict__ out_idx, int* __restrict__ counts) {
    int j = blockIdx.x * 256 + threadIdx.x;
    if (j >= TOT) return;
    int k = j / NPTS;
    atomicAdd(&counts[out_idx[j] * KK + k], 1);
}

__global__ void k_scan1(const int* __restrict__ counts, int* __restrict__ offs,
                        int* __restrict__ bsums) {
    __shared__ int sh[256];
    int t = threadIdx.x;
    int base = blockIdx.x * 1024 + t * 4;
    int v0 = base     < SEGS ? counts[base]     : 0;
    int v1 = base + 1 < SEGS ? counts[base + 1] : 0;
    int v2 = base + 2 < SEGS ? counts[base + 2] : 0;
    int v3 = base + 3 < SEGS ? counts[base + 3] : 0;
    sh[t] = v0 + v1 + v2 + v3;
    __syncthreads();
    for (int o = 1; o < 256; o <<= 1) {
        int pv = (t >= o) ? sh[t - o] : 0;
        __syncthreads();
        sh[t] += pv;
        __syncthreads();
    }
    int ex = (t ? sh[t - 1] : 0);
    if (base     < SEGS) offs[base]     = ex;
    if (base + 1 < SEGS) offs[base + 1] = ex + v0;
    if (base + 2 < SEGS) offs[base + 2] = ex + v0 + v1;
    if (base + 3 < SEGS) offs[base + 3] = ex + v0 + v1 + v2;
    if (t == 255) bsums[blockIdx.x] = sh[255];
}

__global__ void k_scan2(int* __restrict__ bs, int nb) {
    __shared__ int sh[256];
    __shared__ int carry;
    int t = threadIdx.x;
    if (t == 0) carry = 0;
    __syncthreads();
    for (int base = 0; base < nb; base += 256) {
        int v = (base + t < nb) ? bs[base + t] : 0;
        sh[t] = v;
        __syncthreads();
        for (int o = 1; o < 256; o <<= 1) {
            int pv = (t >= o) ? sh[t - o] : 0;
            __syncthreads();
            sh[t] += pv;
            __syncthreads();
        }
        int ex = carry + (t ? sh[t - 1] : 0);
        int tot = sh[255];
        __syncthreads();                 // everyone has read carry & sh
        if (base + t < nb) bs[base + t] = ex;
        if (t == 0) carry += tot;
        __syncthreads();
    }
}

__global__ void k_scan3(int* __restrict__ offs, const int* __restrict__ bsums,
                        int* __restrict__ cursor) {
    int i = blockIdx.x * 256 + threadIdx.x;
    if (i < SEGS) {
        int v = offs[i] + bsums[i >> 10];
        offs[i] = v;
        cursor[i] = v;
    }
    if (i == 0) offs[SEGS] = TOT;
}

__global__ void k_place(const int* __restrict__ out_idx, const int* __restrict__ in_idx,
                        int* __restrict__ cursor, int* __restrict__ entries) {
    int j = blockIdx.x * 256 + threadIdx.x;
    if (j >= TOT) return;
    int k = j / NPTS;
    int seg = out_idx[j] * KK + k;
    int pos = atomicAdd(&cursor[seg], 1);
    entries[pos] = in_idx[j];
}

// ---------------- conv: per-block 128 output rows, loop k, MFMA ----------------
__global__ __launch_bounds__(256) void k_conv(
    const unsigned short* __restrict__ xb,    // [N][64] bf16
    const unsigned short* __restrict__ Wt,    // [27][cout=64][cin=64] bf16
    const int* __restrict__ offs,             // [SEGS+1]
    const int* __restrict__ entries,          // [TOT] src indices
    float* __restrict__ y)                    // [N][64] fp32
{
    __shared__ __align__(16) unsigned short Ash[MT * APAD];
    __shared__ __align__(16) unsigned short Bsh[CC * APAD];
    const int tid  = threadIdx.x;
    const int lane = tid & 63;
    const int wave = tid >> 6;
    const int quad = lane >> 4;
    const int l16  = lane & 15;
    const int i0   = blockIdx.x * MT;

    f32x4 acc[2][4];
#pragma unroll
    for (int mt = 0; mt < 2; ++mt)
#pragma unroll
        for (int nt = 0; nt < 4; ++nt) acc[mt][nt] = (f32x4){0.f, 0.f, 0.f, 0.f};

    const int arow  = tid >> 1;
    const int ahalf = tid & 1;
    const int gi    = i0 + arow;

    for (int k = 0; k < KK; ++k) {
        // stage B: Wt[k] 64x64 bf16, already [cout][cin]
        {
            const u32x4* src = (const u32x4*)(Wt + k * CC * CC);
            u32x4 b0 = src[tid * 2];
            u32x4 b1 = src[tid * 2 + 1];
            int e0 = tid * 16;
            int r = e0 >> 6;
            int c = e0 & 63;
            *(u32x4*)&Bsh[r * APAD + c]     = b0;
            *(u32x4*)&Bsh[r * APAD + c + 8] = b1;
        }
        // stage A: gather-sum x rows for segment (gi, k); 2 threads per row
        {
            u32x4 r0 = (u32x4){0,0,0,0}, r1 = r0, r2 = r0, r3 = r0;
            if (gi < NPTS) {
                int seg = gi * KK + k;
                int b = offs[seg], e = offs[seg + 1];
                if (e - b == 1) {
                    const u32x4* sp = (const u32x4*)(xb + (long)entries[b] * CC + ahalf * 32);
                    r0 = sp[0]; r1 = sp[1]; r2 = sp[2]; r3 = sp[3];
                } else if (e > b) {
                    float a[32];
#pragma unroll
                    for (int q = 0; q < 32; ++q) a[q] = 0.f;
                    for (int jj = b; jj < e; ++jj) {
                        const unsigned short* sp = xb + (long)entries[jj] * CC + ahalf * 32;
#pragma unroll
                        for (int q = 0; q < 32; ++q) a[q] += bf2f(sp[q]);
                    }
                    unsigned int w[16];
#pragma unroll
                    for (int q = 0; q < 16; ++q)
                        w[q] = (unsigned int)f2bf(a[2 * q]) |
                               ((unsigned int)f2bf(a[2 * q + 1]) << 16);
                    r0 = (u32x4){w[0],  w[1],  w[2],  w[3]};
                    r1 = (u32x4){w[4],  w[5],  w[6],  w[7]};
                    r2 = (u32x4){w[8],  w[9],  w[10], w[11]};
                    r3 = (u32x4){w[12], w[13], w[14], w[15]};
                }
            }
            u32x4* dst = (u32x4*)&Ash[arow * APAD + ahalf * 32];
            dst[0] = r0; dst[1] = r1; dst[2] = r2; dst[3] = r3;
        }
        __syncthreads();
        // fragments + MFMA
        bf16x8 afr[2][2], bfr[4][2];
#pragma unroll
        for (int mt = 0; mt < 2; ++mt)
#pragma unroll
            for (int kt = 0; kt < 2; ++kt)
                afr[mt][kt] = *(const bf16x8*)&Ash[(wave * 32 + mt * 16 + l16) * APAD +
                                                   kt * 32 + quad * 8];
#pragma unroll
        for (int nt = 0; nt < 4; ++nt)
#pragma unroll
            for (int kt = 0; kt < 2; ++kt)
                bfr[nt][kt] = *(const bf16x8*)&Bsh[(nt * 16 + l16) * APAD +
                                                   kt * 32 + quad * 8];
#pragma unroll
        for (int mt = 0; mt < 2; ++mt)
#pragma unroll
            for (int nt = 0; nt < 4; ++nt) {
                acc[mt][nt] = __builtin_amdgcn_mfma_f32_16x16x32_bf16(
                    afr[mt][0], bfr[nt][0], acc[mt][nt], 0, 0, 0);
                acc[mt][nt] = __builtin_amdgcn_mfma_f32_16x16x32_bf16(
                    afr[mt][1], bfr[nt][1], acc[mt][nt], 0, 0, 0);
            }
        __syncthreads();
    }
    // epilogue: D row = quad*4 + r, col = l16 (within each 16x16 tile)
#pragma unroll
    for (int mt = 0; mt < 2; ++mt) {
        int rbase = i0 + wave * 32 + mt * 16 + quad * 4;
#pragma unroll
        for (int nt = 0; nt < 4; ++nt) {
            int col = nt * 16 + l16;
#pragma unroll
            for (int r = 0; r < 4; ++r) {
                int gr = rbase + r;
                if (gr < NPTS) y[(long)gr * CC + col] = acc[mt][nt][r];
            }
        }
    }
}

// ---------------- BN ----------------
__global__ void k_bn_stats(const float* __restrict__ y, float* __restrict__ sums) {
    __shared__ float s1[256], s2[256];
    int t = threadIdx.x;
    int c = t & 63, g = t >> 6;
    float a = 0.f, b = 0.f;
    for (int i = blockIdx.x * 4 + g; i < NPTS; i += gridDim.x * 4) {
        float v = y[(long)i * CC + c];
        a += v; b += v * v;
    }
    s1[t] = a; s2[t] = b;
    __syncthreads();
    if (t < 64) {
        a = s1[t] + s1[t + 64] + s1[t + 128] + s1[t + 192];
        b = s2[t] + s2[t + 64] + s2[t + 128] + s2[t + 192];
        atomicAdd(&sums[t], a);
        atomicAdd(&sums[t + 64], b);
    }
}

__global__ void k_bn_fin(const float* __restrict__ sums, const float* __restrict__ gamma,
                         const float* __restrict__ beta, float* __restrict__ sb) {
    int c = threadIdx.x;   // 64 threads
    float mu  = sums[c] * (1.0f / NPTS);
    float var = sums[c + 64] * (1.0f / NPTS) - mu * mu;
    float s = gamma[c] * rsqrtf(var + EPSBN);
    sb[c] = s;
    sb[c + 64] = beta[c] - mu * s;
}

// a1 = bf16(relu(y*s + b))
__global__ void k_apply(const float* __restrict__ y, const float* __restrict__ sb,
                        unsigned short* __restrict__ ab) {
    int id = blockIdx.x * 256 + threadIdx.x;          // 1.6M
    f32x4 v = ((const f32x4*)y)[id];
    int c0 = (id * 4) & 63;
    u16x4 o;
#pragma unroll
    for (int j = 0; j < 4; ++j) {
        float t = fmaxf(v[j] * sb[c0 + j] + sb[64 + c0 + j], 0.f);
        o[j] = f2bf(t);
    }
    ((u16x4*)ab)[id] = o;
}

// out = relu(y*s + b + x)
__global__ void k_final(const float* __restrict__ y, const float* __restrict__ x,
                        const float* __restrict__ sb, float* __restrict__ out) {
    int id = blockIdx.x * 256 + threadIdx.x;          // 1.6M
    f32x4 v  = ((const f32x4*)y)[id];
    f32x4 xv = ((const f32x4*)x)[id];
    int c0 = (id * 4) & 63;
    f32x4 o;
#pragma unroll
    for (int j = 0; j < 4; ++j)
        o[j] = fmaxf(v[j] * sb[c0 + j] + sb[64 + c0 + j] + xv[j], 0.f);
    ((f32x4*)out)[id] = o;
}

extern "C" void kernel_launch(void* const* d_in, const int* in_sizes, int n_in,
                              void* d_out, int out_size, void* d_ws, size_t ws_size,
                              hipStream_t stream) {
    const float* x      = (const float*)d_in[0];
    // d_in[1] = norm_points (unused by the reference math)
    const float* W1     = (const float*)d_in[2];
    const float* gamma1 = (const float*)d_in[3];
    const float* beta1  = (const float*)d_in[4];
    const float* W2     = (const float*)d_in[5];
    const float* gamma2 = (const float*)d_in[6];
    const float* beta2  = (const float*)d_in[7];
    const int* in_idx   = (const int*)d_in[8];
    const int* out_idx  = (const int*)d_in[9];
    float* out = (float*)d_out;

    char* w = (char*)d_ws;
    size_t off = 0;
    auto alloc = [&](size_t bytes) -> char* {
        off = (off + 255) & ~(size_t)255;
        char* p = w + off;
        off += bytes;
        return p;
    };
    int*   counts  = (int*)  alloc((size_t)SEGS * 4);
    float* sums    = (float*)alloc(256 * 4);            // [0:128) layer1, [128:256) layer2
    float* sb      = (float*)alloc(256 * 4);
    int*   offs    = (int*)  alloc(((size_t)SEGS + 1) * 4);
    int*   cursor  = (int*)  alloc((size_t)SEGS * 4);
    int*   entries = (int*)  alloc((size_t)SEGS * 4);
    int*   bsums   = (int*)  alloc(4096 * 4);
    unsigned short* xbf = (unsigned short*)alloc((size_t)NPTS * CC * 2);
    unsigned short* Wt1 = (unsigned short*)alloc((size_t)KK * CC * CC * 2);
    unsigned short* Wt2 = (unsigned short*)alloc((size_t)KK * CC * CC * 2);
    float* y = (float*)alloc((size_t)NPTS * CC * 4);

    // zero counts + sums (covers alignment gap between them)
    size_t zlen = (size_t)((char*)(sums + 256) - (char*)counts);
    hipMemsetAsync(counts, 0, zlen, stream);

    k_convert_x<<<NPTS * CC / 1024, 256, 0, stream>>>(x, xbf);
    k_prep_w<<<(2 * KK * CC * CC) / 256, 256, 0, stream>>>(W1, W2, Wt1, Wt2);
    k_hist<<<(TOT + 255) / 256, 256, 0, stream>>>(out_idx, counts);
    const int NB = (SEGS + 1023) / 1024;
    k_scan1<<<NB, 256, 0, stream>>>(counts, offs, bsums);
    k_scan2<<<1, 256, 0, stream>>>(bsums, NB);
    k_scan3<<<(SEGS + 255) / 256, 256, 0, stream>>>(offs, bsums, cursor);
    k_place<<<(TOT + 255) / 256, 256, 0, stream>>>(out_idx, in_idx, cursor, entries);

    const int CONVB = (NPTS + MT - 1) / MT;
    k_conv<<<CONVB, 256, 0, stream>>>(xbf, Wt1, offs, entries, y);
    k_bn_stats<<<256, 256, 0, stream>>>(y, sums);
    k_bn_fin<<<1, 64, 0, stream>>>(sums, gamma1, beta1, sb);
    k_apply<<<NPTS * CC / 1024, 256, 0, stream>>>(y, sb, xbf);   // a1 overwrites xbf
    k_conv<<<CONVB, 256, 0, stream>>>(xbf, Wt2, offs, entries, y);
    k_bn_stats<<<256, 256, 0, stream>>>(y, sums + 128);
    k_bn_fin<<<1, 64, 0, stream>>>(sums + 128, gamma2, beta2, sb + 128);
    k_final<<<NPTS * CC / 1024, 256, 0, stream>>>(y, x, sb + 128, out);
}

// Round 2
// 840.442 us; speedup vs baseline: 1.0391x; 1.0391x over previous
//
#include <hip/hip_runtime.h>

#define NPTS 100000
#define CC   64
#define KK   27
#define TOT  (KK * NPTS)        // 2,700,000 edges
#define SEGS (NPTS * KK)        // 2,700,000 (k,dst) segments, k-major
#define EPSBN 1e-5f
#define MT   128                // output rows per conv block
#define APAD 72                 // padded LDS row stride in bf16 elems (144B)

typedef float          f32x4  __attribute__((ext_vector_type(4)));
typedef short          bf16x8 __attribute__((ext_vector_type(8)));
typedef unsigned int   u32x4  __attribute__((ext_vector_type(4)));
typedef unsigned short u16x4  __attribute__((ext_vector_type(4)));
typedef int            i32x4  __attribute__((ext_vector_type(4)));

__device__ __forceinline__ float bf2f(unsigned short h) {
    return __uint_as_float(((unsigned int)h) << 16);
}
__device__ __forceinline__ unsigned short f2bf(float f) {
    unsigned int u = __float_as_uint(f);
    u = (u + 0x7fffu + ((u >> 16) & 1u)) >> 16;
    return (unsigned short)u;
}

// ---------------- prep: x -> bf16 ----------------
__global__ void k_convert_x(const float* __restrict__ x, unsigned short* __restrict__ xb) {
    int id = blockIdx.x * 256 + threadIdx.x;          // 1.6M/4 threads, 4 elems each
    f32x4 v = ((const f32x4*)x)[id];
    u16x4 o;
#pragma unroll
    for (int j = 0; j < 4; ++j) o[j] = f2bf(v[j]);
    ((u16x4*)xb)[id] = o;
}

// ---------------- prep: W[k][cin][cout] fp32 -> Wt[k][cout][cin] bf16 (both layers) ---
__global__ void k_prep_w(const float* __restrict__ W1, const float* __restrict__ W2,
                         unsigned short* __restrict__ Wt1, unsigned short* __restrict__ Wt2) {
    int id = blockIdx.x * 256 + threadIdx.x;          // 2*27*4096 threads
    int which = id / (KK * CC * CC);
    int r = id % (KK * CC * CC);
    int k = r / (CC * CC);
    int rem = r % (CC * CC);
    int cin = rem / CC, cout = rem % CC;
    const float* W = which ? W2 : W1;
    unsigned short* Wt = which ? Wt2 : Wt1;
    Wt[k * CC * CC + cout * CC + cin] = f2bf(W[r]);
}

// ---------------- CSR build (k-major segments: seg = k*NPTS + dst) ----------------
// 4 edges per thread; NPTS % 4 == 0 so a 4-group never crosses a k boundary.
__global__ void k_hist(const int* __restrict__ out_idx, int* __restrict__ counts) {
    int id = blockIdx.x * 256 + threadIdx.x;
    int j0 = id * 4;
    if (j0 >= TOT) return;
    int kbase = (j0 / NPTS) * NPTS;                   // k*NPTS
    i32x4 d = ((const i32x4*)out_idx)[id];
#pragma unroll
    for (int q = 0; q < 4; ++q) atomicAdd(&counts[kbase + d[q]], 1);
}

__global__ void k_scan1(const int* __restrict__ counts, int* __restrict__ offs,
                        int* __restrict__ bsums) {
    __shared__ int sh[256];
    int t = threadIdx.x;
    int base = blockIdx.x * 1024 + t * 4;
    int v0 = base     < SEGS ? counts[base]     : 0;
    int v1 = base + 1 < SEGS ? counts[base + 1] : 0;
    int v2 = base + 2 < SEGS ? counts[base + 2] : 0;
    int v3 = base + 3 < SEGS ? counts[base + 3] : 0;
    sh[t] = v0 + v1 + v2 + v3;
    __syncthreads();
    for (int o = 1; o < 256; o <<= 1) {
        int pv = (t >= o) ? sh[t - o] : 0;
        __syncthreads();
        sh[t] += pv;
        __syncthreads();
    }
    int ex = (t ? sh[t - 1] : 0);
    if (base     < SEGS) offs[base]     = ex;
    if (base + 1 < SEGS) offs[base + 1] = ex + v0;
    if (base + 2 < SEGS) offs[base + 2] = ex + v0 + v1;
    if (base + 3 < SEGS) offs[base + 3] = ex + v0 + v1 + v2;
    if (t == 255) bsums[blockIdx.x] = sh[255];
}

__global__ void k_scan2(int* __restrict__ bs, int nb) {
    __shared__ int sh[256];
    __shared__ int carry;
    int t = threadIdx.x;
    if (t == 0) carry = 0;
    __syncthreads();
    for (int base = 0; base < nb; base += 256) {
        int v = (base + t < nb) ? bs[base + t] : 0;
        sh[t] = v;
        __syncthreads();
        for (int o = 1; o < 256; o <<= 1) {
            int pv = (t >= o) ? sh[t - o] : 0;
            __syncthreads();
            sh[t] += pv;
            __syncthreads();
        }
        int ex = carry + (t ? sh[t - 1] : 0);
        int tot = sh[255];
        __syncthreads();                 // everyone has read carry & sh
        if (base + t < nb) bs[base + t] = ex;
        if (t == 0) carry += tot;
        __syncthreads();
    }
}

__global__ void k_scan3(int* __restrict__ offs, const int* __restrict__ bsums,
                        int* __restrict__ cursor) {
    int i = blockIdx.x * 256 + threadIdx.x;
    if (i < SEGS) {
        int v = offs[i] + bsums[i >> 10];
        offs[i] = v;
        cursor[i] = v;
    }
    if (i == 0) offs[SEGS] = TOT;
}

__global__ void k_place(const int* __restrict__ out_idx, const int* __restrict__ in_idx,
                        int* __restrict__ cursor, int* __restrict__ entries) {
    int id = blockIdx.x * 256 + threadIdx.x;
    int j0 = id * 4;
    if (j0 >= TOT) return;
    int kbase = (j0 / NPTS) * NPTS;
    i32x4 d = ((const i32x4*)out_idx)[id];
    i32x4 s = ((const i32x4*)in_idx)[id];
#pragma unroll
    for (int q = 0; q < 4; ++q) {
        int pos = atomicAdd(&cursor[kbase + d[q]], 1);
        entries[pos] = s[q];
    }
}

// ---------------- conv: per-block 128 output rows, loop k, MFMA ----------------
__global__ __launch_bounds__(256) void k_conv(
    const unsigned short* __restrict__ xb,    // [N][64] bf16
    const unsigned short* __restrict__ Wt,    // [27][cout=64][cin=64] bf16
    const int* __restrict__ offs,             // [SEGS+1], k-major
    const int* __restrict__ entries,          // [TOT] src indices
    float* __restrict__ y)                    // [N][64] fp32
{
    __shared__ __align__(16) unsigned short Ash[MT * APAD];
    __shared__ __align__(16) unsigned short Bsh[CC * APAD];
    const int tid  = threadIdx.x;
    const int lane = tid & 63;
    const int wave = tid >> 6;
    const int quad = lane >> 4;
    const int l16  = lane & 15;
    const int i0   = blockIdx.x * MT;

    f32x4 acc[2][4];
#pragma unroll
    for (int mt = 0; mt < 2; ++mt)
#pragma unroll
        for (int nt = 0; nt < 4; ++nt) acc[mt][nt] = (f32x4){0.f, 0.f, 0.f, 0.f};

    const int arow  = tid >> 1;
    const int ahalf = tid & 1;
    const int gi    = i0 + arow;

    for (int k = 0; k < KK; ++k) {
        // stage B: Wt[k] 64x64 bf16, already [cout][cin]
        {
            const u32x4* src = (const u32x4*)(Wt + k * CC * CC);
            u32x4 b0 = src[tid * 2];
            u32x4 b1 = src[tid * 2 + 1];
            int e0 = tid * 16;
            int r = e0 >> 6;
            int c = e0 & 63;
            *(u32x4*)&Bsh[r * APAD + c]     = b0;
            *(u32x4*)&Bsh[r * APAD + c + 8] = b1;
        }
        // stage A: gather-sum x rows for segment (k, gi); 2 threads per row
        {
            u32x4 r0 = (u32x4){0,0,0,0}, r1 = r0, r2 = r0, r3 = r0;
            if (gi < NPTS) {
                int seg = k * NPTS + gi;
                int b = offs[seg], e = offs[seg + 1];
                if (e - b == 1) {
                    const u32x4* sp = (const u32x4*)(xb + (long)entries[b] * CC + ahalf * 32);
                    r0 = sp[0]; r1 = sp[1]; r2 = sp[2]; r3 = sp[3];
                } else if (e > b) {
                    float a[32];
#pragma unroll
                    for (int q = 0; q < 32; ++q) a[q] = 0.f;
                    for (int jj = b; jj < e; ++jj) {
                        const unsigned short* sp = xb + (long)entries[jj] * CC + ahalf * 32;
#pragma unroll
                        for (int q = 0; q < 32; ++q) a[q] += bf2f(sp[q]);
                    }
                    unsigned int w[16];
#pragma unroll
                    for (int q = 0; q < 16; ++q)
                        w[q] = (unsigned int)f2bf(a[2 * q]) |
                               ((unsigned int)f2bf(a[2 * q + 1]) << 16);
                    r0 = (u32x4){w[0],  w[1],  w[2],  w[3]};
                    r1 = (u32x4){w[4],  w[5],  w[6],  w[7]};
                    r2 = (u32x4){w[8],  w[9],  w[10], w[11]};
                    r3 = (u32x4){w[12], w[13], w[14], w[15]};
                }
            }
            u32x4* dst = (u32x4*)&Ash[arow * APAD + ahalf * 32];
            dst[0] = r0; dst[1] = r1; dst[2] = r2; dst[3] = r3;
        }
        __syncthreads();
        // fragments + MFMA
        bf16x8 afr[2][2], bfr[4][2];
#pragma unroll
        for (int mt = 0; mt < 2; ++mt)
#pragma unroll
            for (int kt = 0; kt < 2; ++kt)
                afr[mt][kt] = *(const bf16x8*)&Ash[(wave * 32 + mt * 16 + l16) * APAD +
                                                   kt * 32 + quad * 8];
#pragma unroll
        for (int nt = 0; nt < 4; ++nt)
#pragma unroll
            for (int kt = 0; kt < 2; ++kt)
                bfr[nt][kt] = *(const bf16x8*)&Bsh[(nt * 16 + l16) * APAD +
                                                   kt * 32 + quad * 8];
#pragma unroll
        for (int mt = 0; mt < 2; ++mt)
#pragma unroll
            for (int nt = 0; nt < 4; ++nt) {
                acc[mt][nt] = __builtin_amdgcn_mfma_f32_16x16x32_bf16(
                    afr[mt][0], bfr[nt][0], acc[mt][nt], 0, 0, 0);
                acc[mt][nt] = __builtin_amdgcn_mfma_f32_16x16x32_bf16(
                    afr[mt][1], bfr[nt][1], acc[mt][nt], 0, 0, 0);
            }
        __syncthreads();
    }
    // epilogue: D row = quad*4 + r, col = l16 (within each 16x16 tile)
#pragma unroll
    for (int mt = 0; mt < 2; ++mt) {
        int rbase = i0 + wave * 32 + mt * 16 + quad * 4;
#pragma unroll
        for (int nt = 0; nt < 4; ++nt) {
            int col = nt * 16 + l16;
#pragma unroll
            for (int r = 0; r < 4; ++r) {
                int gr = rbase + r;
                if (gr < NPTS) y[(long)gr * CC + col] = acc[mt][nt][r];
            }
        }
    }
}

// ---------------- BN ----------------
__global__ void k_bn_stats(const float* __restrict__ y, float* __restrict__ sums) {
    __shared__ float s1[256], s2[256];
    int t = threadIdx.x;
    int c = t & 63, g = t >> 6;
    float a = 0.f, b = 0.f;
    for (int i = blockIdx.x * 4 + g; i < NPTS; i += gridDim.x * 4) {
        float v = y[(long)i * CC + c];
        a += v; b += v * v;
    }
    s1[t] = a; s2[t] = b;
    __syncthreads();
    if (t < 64) {
        a = s1[t] + s1[t + 64] + s1[t + 128] + s1[t + 192];
        b = s2[t] + s2[t + 64] + s2[t + 128] + s2[t + 192];
        atomicAdd(&sums[t], a);
        atomicAdd(&sums[t + 64], b);
    }
}

__global__ void k_bn_fin(const float* __restrict__ sums, const float* __restrict__ gamma,
                         const float* __restrict__ beta, float* __restrict__ sb) {
    int c = threadIdx.x;   // 64 threads
    float mu  = sums[c] * (1.0f / NPTS);
    float var = sums[c + 64] * (1.0f / NPTS) - mu * mu;
    float s = gamma[c] * rsqrtf(var + EPSBN);
    sb[c] = s;
    sb[c + 64] = beta[c] - mu * s;
}

// a1 = bf16(relu(y*s + b))
__global__ void k_apply(const float* __restrict__ y, const float* __restrict__ sb,
                        unsigned short* __restrict__ ab) {
    int id = blockIdx.x * 256 + threadIdx.x;          // 1.6M/4
    f32x4 v = ((const f32x4*)y)[id];
    int c0 = (id * 4) & 63;
    u16x4 o;
#pragma unroll
    for (int j = 0; j < 4; ++j) {
        float t = fmaxf(v[j] * sb[c0 + j] + sb[64 + c0 + j], 0.f);
        o[j] = f2bf(t);
    }
    ((u16x4*)ab)[id] = o;
}

// out = relu(y*s + b + x)
__global__ void k_final(const float* __restrict__ y, const float* __restrict__ x,
                        const float* __restrict__ sb, float* __restrict__ out) {
    int id = blockIdx.x * 256 + threadIdx.x;          // 1.6M/4
    f32x4 v  = ((const f32x4*)y)[id];
    f32x4 xv = ((const f32x4*)x)[id];
    int c0 = (id * 4) & 63;
    f32x4 o;
#pragma unroll
    for (int j = 0; j < 4; ++j)
        o[j] = fmaxf(v[j] * sb[c0 + j] + sb[64 + c0 + j] + xv[j], 0.f);
    ((f32x4*)out)[id] = o;
}

extern "C" void kernel_launch(void* const* d_in, const int* in_sizes, int n_in,
                              void* d_out, int out_size, void* d_ws, size_t ws_size,
                              hipStream_t stream) {
    const float* x      = (const float*)d_in[0];
    // d_in[1] = norm_points (unused by the reference math)
    const float* W1     = (const float*)d_in[2];
    const float* gamma1 = (const float*)d_in[3];
    const float* beta1  = (const float*)d_in[4];
    const float* W2     = (const float*)d_in[5];
    const float* gamma2 = (const float*)d_in[6];
    const float* beta2  = (const float*)d_in[7];
    const int* in_idx   = (const int*)d_in[8];
    const int* out_idx  = (const int*)d_in[9];
    float* out = (float*)d_out;

    char* w = (char*)d_ws;
    size_t off = 0;
    auto alloc = [&](size_t bytes) -> char* {
        off = (off + 255) & ~(size_t)255;
        char* p = w + off;
        off += bytes;
        return p;
    };
    int*   counts  = (int*)  alloc((size_t)SEGS * 4);
    float* sums    = (float*)alloc(256 * 4);            // [0:128) layer1, [128:256) layer2
    float* sb      = (float*)alloc(256 * 4);
    int*   offs    = (int*)  alloc(((size_t)SEGS + 1) * 4);
    int*   cursor  = (int*)  alloc((size_t)SEGS * 4);
    int*   entries = (int*)  alloc((size_t)SEGS * 4);
    int*   bsums   = (int*)  alloc(4096 * 4);
    unsigned short* xbf = (unsigned short*)alloc((size_t)NPTS * CC * 2);
    unsigned short* Wt1 = (unsigned short*)alloc((size_t)KK * CC * CC * 2);
    unsigned short* Wt2 = (unsigned short*)alloc((size_t)KK * CC * CC * 2);
    float* y = (float*)alloc((size_t)NPTS * CC * 4);

    // zero counts + sums (covers alignment gap between them)
    size_t zlen = (size_t)((char*)(sums + 256) - (char*)counts);
    hipMemsetAsync(counts, 0, zlen, stream);

    k_convert_x<<<NPTS * CC / 1024, 256, 0, stream>>>(x, xbf);
    k_prep_w<<<(2 * KK * CC * CC) / 256, 256, 0, stream>>>(W1, W2, Wt1, Wt2);
    k_hist<<<(TOT / 4 + 255) / 256, 256, 0, stream>>>(out_idx, counts);
    const int NB = (SEGS + 1023) / 1024;
    k_scan1<<<NB, 256, 0, stream>>>(counts, offs, bsums);
    k_scan2<<<1, 256, 0, stream>>>(bsums, NB);
    k_scan3<<<(SEGS + 255) / 256, 256, 0, stream>>>(offs, bsums, cursor);
    k_place<<<(TOT / 4 + 255) / 256, 256, 0, stream>>>(out_idx, in_idx, cursor, entries);

    const int CONVB = (NPTS + MT - 1) / MT;
    k_conv<<<CONVB, 256, 0, stream>>>(xbf, Wt1, offs, entries, y);
    k_bn_stats<<<256, 256, 0, stream>>>(y, sums);
    k_bn_fin<<<1, 64, 0, stream>>>(sums, gamma1, beta1, sb);
    k_apply<<<NPTS * CC / 1024, 256, 0, stream>>>(y, sb, xbf);   // a1 overwrites xbf
    k_conv<<<CONVB, 256, 0, stream>>>(xbf, Wt2, offs, entries, y);
    k_bn_stats<<<256, 256, 0, stream>>>(y, sums + 128);
    k_bn_fin<<<1, 64, 0, stream>>>(sums + 128, gamma2, beta2, sb + 128);
    k_final<<<NPTS * CC / 1024, 256, 0, stream>>>(y, x, sb + 128, out);
}

// Round 3
// 599.177 us; speedup vs baseline: 1.4575x; 1.4027x over previous
//
#include <hip/hip_runtime.h>

#define NPTS 100000
#define CC   64
#define KK   27
#define TOT  (KK * NPTS)        // 2,700,000 edges
#define SEGS (NPTS * KK)        // 2,700,000 (k,dst) segments, k-major
#define EPSBN 1e-5f
#define MT   128                // output rows per conv block
#define APAD 72                 // padded LDS row stride in bf16 elems (144B)

#define NRANGE 32               // dst ranges per slice
#define RSIZE  (NPTS / NRANGE)  // 3125 dsts per range
#define CAP    4608             // LDS edge-list capacity (mean 3125, 26 sigma headroom)
#define CHUNK  12500            // edges per k_rhist block (divides NPTS)

typedef float          f32x4  __attribute__((ext_vector_type(4)));
typedef short          bf16x8 __attribute__((ext_vector_type(8)));
typedef unsigned int   u32x4  __attribute__((ext_vector_type(4)));
typedef unsigned short u16x4  __attribute__((ext_vector_type(4)));
typedef int            i32x4  __attribute__((ext_vector_type(4)));

__device__ __forceinline__ float bf2f(unsigned short h) {
    return __uint_as_float(((unsigned int)h) << 16);
}
__device__ __forceinline__ unsigned short f2bf(float f) {
    unsigned int u = __float_as_uint(f);
    u = (u + 0x7fffu + ((u >> 16) & 1u)) >> 16;
    return (unsigned short)u;
}

// ---------------- prep: x -> bf16 ----------------
__global__ void k_convert_x(const float* __restrict__ x, unsigned short* __restrict__ xb) {
    int id = blockIdx.x * 256 + threadIdx.x;
    f32x4 v = ((const f32x4*)x)[id];
    u16x4 o;
#pragma unroll
    for (int j = 0; j < 4; ++j) o[j] = f2bf(v[j]);
    ((u16x4*)xb)[id] = o;
}

// ---------------- prep: W[k][cin][cout] fp32 -> Wt[k][cout][cin] bf16 ----------------
__global__ void k_prep_w(const float* __restrict__ W1, const float* __restrict__ W2,
                         unsigned short* __restrict__ Wt1, unsigned short* __restrict__ Wt2) {
    int id = blockIdx.x * 256 + threadIdx.x;
    int which = id / (KK * CC * CC);
    int r = id % (KK * CC * CC);
    int k = r / (CC * CC);
    int rem = r % (CC * CC);
    int cin = rem / CC, cout = rem % CC;
    const float* W = which ? W2 : W1;
    unsigned short* Wt = which ? Wt2 : Wt1;
    Wt[k * CC * CC + cout * CC + cin] = f2bf(W[r]);
}

// ---------------- CSR build v2: per-(k,range) counting sort ----------------
// Phase 1: per-(k,range) totals. One block = 12500 edges within one slice.
__global__ void k_rhist(const int* __restrict__ out_idx, int* __restrict__ rcnt) {
    __shared__ int rc[NRANGE];
    int t = threadIdx.x;
    if (t < NRANGE) rc[t] = 0;
    __syncthreads();
    int j0 = blockIdx.x * CHUNK;               // slice-aligned chunk
    int k = j0 / NPTS;
    const i32x4* src = (const i32x4*)(out_idx + j0);
    for (int ii = t; ii < CHUNK / 4; ii += 256) {
        i32x4 d = src[ii];
#pragma unroll
        for (int q = 0; q < 4; ++q) atomicAdd(&rc[d[q] / RSIZE], 1);
    }
    __syncthreads();
    if (t < NRANGE) atomicAdd(&rcnt[k * NRANGE + t], rc[t]);
}

// Phase 2: per-slice exclusive scan of the 32 range counts -> global bases.
__global__ void k_rscan(const int* __restrict__ rcnt, int* __restrict__ rbase,
                        int* __restrict__ offs) {
    int t = threadIdx.x;
    if (t < KK) {
        int run = t * NPTS;
        for (int r = 0; r < NRANGE; ++r) {
            rbase[t * NRANGE + r] = run;
            run += rcnt[t * NRANGE + r];
        }
    }
    if (t == 0) offs[SEGS] = TOT;
}

// Phase 3: one block per (k,range): scan slice, counting-sort in LDS,
// write offs + entries into the block's private contiguous region.
__global__ __launch_bounds__(256) void k_sort(
    const int* __restrict__ out_idx, const int* __restrict__ in_idx,
    const int* __restrict__ rbase,
    int* __restrict__ offs, int* __restrict__ entries) {
    __shared__ int cnt[RSIZE];            // 12.5 KB: counts -> cursors (global pos)
    __shared__ unsigned list[CAP];        // 18 KB: packed (dloc<<17)|src
    __shared__ int psum[256];
    __shared__ int nlist;

    const int t = threadIdx.x;
    const int k = blockIdx.x / NRANGE;
    const int r = blockIdx.x % NRANGE;
    const int dlo = r * RSIZE;

    for (int i = t; i < RSIZE; i += 256) cnt[i] = 0;
    if (t == 0) nlist = 0;
    __syncthreads();

    // single coalesced pass over the slice
    const i32x4* dsrc = (const i32x4*)(out_idx + k * NPTS);
    const i32x4* ssrc = (const i32x4*)(in_idx + k * NPTS);
    for (int ii = t; ii < NPTS / 4; ii += 256) {
        i32x4 d4 = dsrc[ii];
        i32x4 s4 = ssrc[ii];
#pragma unroll
        for (int q = 0; q < 4; ++q) {
            unsigned dloc = (unsigned)(d4[q] - dlo);
            if (dloc < RSIZE) {
                atomicAdd(&cnt[dloc], 1);
                int p = atomicAdd(&nlist, 1);
                if (p < CAP) list[p] = (dloc << 17) | (unsigned)s4[q];
            }
        }
    }
    __syncthreads();

    // exclusive scan of cnt[0..RSIZE), write offs, convert cnt -> global cursor
    const int T = (RSIZE + 255) / 256;    // 13
    int vals[T];
    int s = 0;
#pragma unroll
    for (int q = 0; q < T; ++q) {
        int i = t * T + q;
        int v = (i < RSIZE) ? cnt[i] : 0;
        vals[q] = v;
        s += v;
    }
    psum[t] = s;
    __syncthreads();
    for (int o = 1; o < 256; o <<= 1) {
        int pv = (t >= o) ? psum[t - o] : 0;
        __syncthreads();
        psum[t] += pv;
        __syncthreads();
    }
    int run = rbase[blockIdx.x] + (t ? psum[t - 1] : 0);
#pragma unroll
    for (int q = 0; q < T; ++q) {
        int i = t * T + q;
        if (i < RSIZE) {
            offs[k * NPTS + dlo + i] = run;
            cnt[i] = run;
            run += vals[q];
        }
    }
    __syncthreads();

    // placement: scatter confined to this block's contiguous entries region
    int nl = nlist < CAP ? nlist : CAP;
    for (int i = t; i < nl; i += 256) {
        unsigned u = list[i];
        int dloc = u >> 17;
        int src = u & 0x1FFFF;
        int p = atomicAdd(&cnt[dloc], 1);
        entries[p] = src;
    }
}

// ---------------- conv: per-block 128 output rows, loop k, MFMA ----------------
__global__ __launch_bounds__(256) void k_conv(
    const unsigned short* __restrict__ xb,    // [N][64] bf16
    const unsigned short* __restrict__ Wt,    // [27][cout=64][cin=64] bf16
    const int* __restrict__ offs,             // [SEGS+1], k-major
    const int* __restrict__ entries,          // [TOT] src indices
    float* __restrict__ y)                    // [N][64] fp32
{
    __shared__ __align__(16) unsigned short Ash[MT * APAD];
    __shared__ __align__(16) unsigned short Bsh[CC * APAD];
    const int tid  = threadIdx.x;
    const int lane = tid & 63;
    const int wave = tid >> 6;
    const int quad = lane >> 4;
    const int l16  = lane & 15;
    const int i0   = blockIdx.x * MT;

    f32x4 acc[2][4];
#pragma unroll
    for (int mt = 0; mt < 2; ++mt)
#pragma unroll
        for (int nt = 0; nt < 4; ++nt) acc[mt][nt] = (f32x4){0.f, 0.f, 0.f, 0.f};

    const int arow  = tid >> 1;
    const int ahalf = tid & 1;
    const int gi    = i0 + arow;

    for (int k = 0; k < KK; ++k) {
        // stage B: Wt[k] 64x64 bf16, already [cout][cin]
        {
            const u32x4* src = (const u32x4*)(Wt + k * CC * CC);
            u32x4 b0 = src[tid * 2];
            u32x4 b1 = src[tid * 2 + 1];
            int e0 = tid * 16;
            int rr = e0 >> 6;
            int c = e0 & 63;
            *(u32x4*)&Bsh[rr * APAD + c]     = b0;
            *(u32x4*)&Bsh[rr * APAD + c + 8] = b1;
        }
        // stage A: gather-sum x rows for segment (k, gi); 2 threads per row
        {
            u32x4 r0 = (u32x4){0,0,0,0}, r1 = r0, r2 = r0, r3 = r0;
            if (gi < NPTS) {
                int seg = k * NPTS + gi;
                int b = offs[seg], e = offs[seg + 1];
                if (e - b == 1) {
                    const u32x4* sp = (const u32x4*)(xb + (long)entries[b] * CC + ahalf * 32);
                    r0 = sp[0]; r1 = sp[1]; r2 = sp[2]; r3 = sp[3];
                } else if (e > b) {
                    float a[32];
#pragma unroll
                    for (int q = 0; q < 32; ++q) a[q] = 0.f;
                    for (int jj = b; jj < e; ++jj) {
                        const unsigned short* sp = xb + (long)entries[jj] * CC + ahalf * 32;
#pragma unroll
                        for (int q = 0; q < 32; ++q) a[q] += bf2f(sp[q]);
                    }
                    unsigned int w[16];
#pragma unroll
                    for (int q = 0; q < 16; ++q)
                        w[q] = (unsigned int)f2bf(a[2 * q]) |
                               ((unsigned int)f2bf(a[2 * q + 1]) << 16);
                    r0 = (u32x4){w[0],  w[1],  w[2],  w[3]};
                    r1 = (u32x4){w[4],  w[5],  w[6],  w[7]};
                    r2 = (u32x4){w[8],  w[9],  w[10], w[11]};
                    r3 = (u32x4){w[12], w[13], w[14], w[15]};
                }
            }
            u32x4* dst = (u32x4*)&Ash[arow * APAD + ahalf * 32];
            dst[0] = r0; dst[1] = r1; dst[2] = r2; dst[3] = r3;
        }
        __syncthreads();
        // fragments + MFMA
        bf16x8 afr[2][2], bfr[4][2];
#pragma unroll
        for (int mt = 0; mt < 2; ++mt)
#pragma unroll
            for (int kt = 0; kt < 2; ++kt)
                afr[mt][kt] = *(const bf16x8*)&Ash[(wave * 32 + mt * 16 + l16) * APAD +
                                                   kt * 32 + quad * 8];
#pragma unroll
        for (int nt = 0; nt < 4; ++nt)
#pragma unroll
            for (int kt = 0; kt < 2; ++kt)
                bfr[nt][kt] = *(const bf16x8*)&Bsh[(nt * 16 + l16) * APAD +
                                                   kt * 32 + quad * 8];
#pragma unroll
        for (int mt = 0; mt < 2; ++mt)
#pragma unroll
            for (int nt = 0; nt < 4; ++nt) {
                acc[mt][nt] = __builtin_amdgcn_mfma_f32_16x16x32_bf16(
                    afr[mt][0], bfr[nt][0], acc[mt][nt], 0, 0, 0);
                acc[mt][nt] = __builtin_amdgcn_mfma_f32_16x16x32_bf16(
                    afr[mt][1], bfr[nt][1], acc[mt][nt], 0, 0, 0);
            }
        __syncthreads();
    }
    // epilogue: D row = quad*4 + r, col = l16 (within each 16x16 tile)
#pragma unroll
    for (int mt = 0; mt < 2; ++mt) {
        int rbase_ = i0 + wave * 32 + mt * 16 + quad * 4;
#pragma unroll
        for (int nt = 0; nt < 4; ++nt) {
            int col = nt * 16 + l16;
#pragma unroll
            for (int rr = 0; rr < 4; ++rr) {
                int gr = rbase_ + rr;
                if (gr < NPTS) y[(long)gr * CC + col] = acc[mt][nt][rr];
            }
        }
    }
}

// ---------------- BN ----------------
__global__ void k_bn_stats(const float* __restrict__ y, float* __restrict__ sums) {
    __shared__ float s1[256], s2[256];
    int t = threadIdx.x;
    int c = t & 63, g = t >> 6;
    float a = 0.f, b = 0.f;
    for (int i = blockIdx.x * 4 + g; i < NPTS; i += gridDim.x * 4) {
        float v = y[(long)i * CC + c];
        a += v; b += v * v;
    }
    s1[t] = a; s2[t] = b;
    __syncthreads();
    if (t < 64) {
        a = s1[t] + s1[t + 64] + s1[t + 128] + s1[t + 192];
        b = s2[t] + s2[t + 64] + s2[t + 128] + s2[t + 192];
        atomicAdd(&sums[t], a);
        atomicAdd(&sums[t + 64], b);
    }
}

__global__ void k_bn_fin(const float* __restrict__ sums, const float* __restrict__ gamma,
                         const float* __restrict__ beta, float* __restrict__ sb) {
    int c = threadIdx.x;   // 64 threads
    float mu  = sums[c] * (1.0f / NPTS);
    float var = sums[c + 64] * (1.0f / NPTS) - mu * mu;
    float s = gamma[c] * rsqrtf(var + EPSBN);
    sb[c] = s;
    sb[c + 64] = beta[c] - mu * s;
}

// a1 = bf16(relu(y*s + b))
__global__ void k_apply(const float* __restrict__ y, const float* __restrict__ sb,
                        unsigned short* __restrict__ ab) {
    int id = blockIdx.x * 256 + threadIdx.x;
    f32x4 v = ((const f32x4*)y)[id];
    int c0 = (id * 4) & 63;
    u16x4 o;
#pragma unroll
    for (int j = 0; j < 4; ++j) {
        float t = fmaxf(v[j] * sb[c0 + j] + sb[64 + c0 + j], 0.f);
        o[j] = f2bf(t);
    }
    ((u16x4*)ab)[id] = o;
}

// out = relu(y*s + b + x)
__global__ void k_final(const float* __restrict__ y, const float* __restrict__ x,
                        const float* __restrict__ sb, float* __restrict__ out) {
    int id = blockIdx.x * 256 + threadIdx.x;
    f32x4 v  = ((const f32x4*)y)[id];
    f32x4 xv = ((const f32x4*)x)[id];
    int c0 = (id * 4) & 63;
    f32x4 o;
#pragma unroll
    for (int j = 0; j < 4; ++j)
        o[j] = fmaxf(v[j] * sb[c0 + j] + sb[64 + c0 + j] + xv[j], 0.f);
    ((f32x4*)out)[id] = o;
}

extern "C" void kernel_launch(void* const* d_in, const int* in_sizes, int n_in,
                              void* d_out, int out_size, void* d_ws, size_t ws_size,
                              hipStream_t stream) {
    const float* x      = (const float*)d_in[0];
    // d_in[1] = norm_points (unused by the reference math)
    const float* W1     = (const float*)d_in[2];
    const float* gamma1 = (const float*)d_in[3];
    const float* beta1  = (const float*)d_in[4];
    const float* W2     = (const float*)d_in[5];
    const float* gamma2 = (const float*)d_in[6];
    const float* beta2  = (const float*)d_in[7];
    const int* in_idx   = (const int*)d_in[8];
    const int* out_idx  = (const int*)d_in[9];
    float* out = (float*)d_out;

    char* w = (char*)d_ws;
    size_t off = 0;
    auto alloc = [&](size_t bytes) -> char* {
        off = (off + 255) & ~(size_t)255;
        char* p = w + off;
        off += bytes;
        return p;
    };
    int*   rcnt    = (int*)  alloc((size_t)KK * NRANGE * 4);
    float* sums    = (float*)alloc(256 * 4);            // [0:128) layer1, [128:256) layer2
    int*   rbase   = (int*)  alloc((size_t)KK * NRANGE * 4);
    float* sb      = (float*)alloc(256 * 4);
    int*   offs    = (int*)  alloc(((size_t)SEGS + 1) * 4);
    int*   entries = (int*)  alloc((size_t)SEGS * 4);
    unsigned short* xbf = (unsigned short*)alloc((size_t)NPTS * CC * 2);
    unsigned short* Wt1 = (unsigned short*)alloc((size_t)KK * CC * CC * 2);
    unsigned short* Wt2 = (unsigned short*)alloc((size_t)KK * CC * CC * 2);
    float* y = (float*)alloc((size_t)NPTS * CC * 4);

    // zero rcnt + sums (contiguous; covers alignment gap)
    size_t zlen = (size_t)((char*)(sums + 256) - (char*)rcnt);
    hipMemsetAsync(rcnt, 0, zlen, stream);

    k_convert_x<<<NPTS * CC / 1024, 256, 0, stream>>>(x, xbf);
    k_prep_w<<<(2 * KK * CC * CC) / 256, 256, 0, stream>>>(W1, W2, Wt1, Wt2);
    k_rhist<<<TOT / CHUNK, 256, 0, stream>>>(out_idx, rcnt);
    k_rscan<<<1, 64, 0, stream>>>(rcnt, rbase, offs);
    k_sort<<<KK * NRANGE, 256, 0, stream>>>(out_idx, in_idx, rbase, offs, entries);

    const int CONVB = (NPTS + MT - 1) / MT;
    k_conv<<<CONVB, 256, 0, stream>>>(xbf, Wt1, offs, entries, y);
    k_bn_stats<<<256, 256, 0, stream>>>(y, sums);
    k_bn_fin<<<1, 64, 0, stream>>>(sums, gamma1, beta1, sb);
    k_apply<<<NPTS * CC / 1024, 256, 0, stream>>>(y, sb, xbf);   // a1 overwrites xbf
    k_conv<<<CONVB, 256, 0, stream>>>(xbf, Wt2, offs, entries, y);
    k_bn_stats<<<256, 256, 0, stream>>>(y, sums + 128);
    k_bn_fin<<<1, 64, 0, stream>>>(sums + 128, gamma2, beta2, sb + 128);
    k_final<<<NPTS * CC / 1024, 256, 0, stream>>>(y, x, sb + 128, out);
}

// Round 4
// 567.888 us; speedup vs baseline: 1.5378x; 1.0551x over previous
//
#include <hip/hip_runtime.h>

#define NPTS 100000
#define CC   64
#define KK   27
#define TOT  (KK * NPTS)        // 2,700,000 edges
#define SEGS (NPTS * KK)        // 2,700,000 (k,dst) segments, k-major
#define EPSBN 1e-5f
#define MT   128                // output rows per conv block
#define APAD 72                 // padded LDS row stride in bf16 elems (144B)

#define NRANGE 32               // dst ranges per slice
#define RSIZE  (NPTS / NRANGE)  // 3125 dsts per range
#define CAP    4608             // LDS edge-list capacity
#define CHUNK  12500            // edges per k_rhist block (divides NPTS)

typedef float          f32x4  __attribute__((ext_vector_type(4)));
typedef short          bf16x8 __attribute__((ext_vector_type(8)));
typedef unsigned int   u32x4  __attribute__((ext_vector_type(4)));
typedef unsigned short u16x4  __attribute__((ext_vector_type(4)));
typedef int            i32x4  __attribute__((ext_vector_type(4)));

__device__ __forceinline__ float bf2f(unsigned short h) {
    return __uint_as_float(((unsigned int)h) << 16);
}
__device__ __forceinline__ unsigned short f2bf(float f) {
    unsigned int u = __float_as_uint(f);
    u = (u + 0x7fffu + ((u >> 16) & 1u)) >> 16;
    return (unsigned short)u;
}

// barrier that drains LDS only (lgkmcnt(0)) — keeps global prefetches in flight.
// simm16: vmcnt=63 (no wait) [15:14]|[3:0], expcnt=7 [6:4], lgkmcnt=0 [11:8] -> 0xC07F
__device__ __forceinline__ void lds_barrier() {
    asm volatile("" ::: "memory");
    __builtin_amdgcn_s_waitcnt(0xC07F);
    __builtin_amdgcn_s_barrier();
    asm volatile("" ::: "memory");
}

// ---------------- prep: x -> bf16 ----------------
__global__ void k_convert_x(const float* __restrict__ x, unsigned short* __restrict__ xb) {
    int id = blockIdx.x * 256 + threadIdx.x;
    f32x4 v = ((const f32x4*)x)[id];
    u16x4 o;
#pragma unroll
    for (int j = 0; j < 4; ++j) o[j] = f2bf(v[j]);
    ((u16x4*)xb)[id] = o;
}

// ---------------- prep: W[k][cin][cout] fp32 -> Wt[k][cout][cin] bf16 ----------------
__global__ void k_prep_w(const float* __restrict__ W1, const float* __restrict__ W2,
                         unsigned short* __restrict__ Wt1, unsigned short* __restrict__ Wt2) {
    int id = blockIdx.x * 256 + threadIdx.x;
    int which = id / (KK * CC * CC);
    int r = id % (KK * CC * CC);
    int k = r / (CC * CC);
    int rem = r % (CC * CC);
    int cin = rem / CC, cout = rem % CC;
    const float* W = which ? W2 : W1;
    unsigned short* Wt = which ? Wt2 : Wt1;
    Wt[k * CC * CC + cout * CC + cin] = f2bf(W[r]);
}

// ---------------- CSR build: per-(k,range) counting sort ----------------
__global__ void k_rhist(const int* __restrict__ out_idx, int* __restrict__ rcnt) {
    __shared__ int rc[NRANGE];
    int t = threadIdx.x;
    if (t < NRANGE) rc[t] = 0;
    __syncthreads();
    int j0 = blockIdx.x * CHUNK;
    int k = j0 / NPTS;
    const i32x4* src = (const i32x4*)(out_idx + j0);
    for (int ii = t; ii < CHUNK / 4; ii += 256) {
        i32x4 d = src[ii];
#pragma unroll
        for (int q = 0; q < 4; ++q) atomicAdd(&rc[d[q] / RSIZE], 1);
    }
    __syncthreads();
    if (t < NRANGE) atomicAdd(&rcnt[k * NRANGE + t], rc[t]);
}

__global__ void k_rscan(const int* __restrict__ rcnt, int* __restrict__ rbase,
                        int* __restrict__ offs) {
    int t = threadIdx.x;
    if (t < KK) {
        int run = t * NPTS;
        for (int r = 0; r < NRANGE; ++r) {
            rbase[t * NRANGE + r] = run;
            run += rcnt[t * NRANGE + r];
        }
    }
    if (t == 0) offs[SEGS] = TOT;
}

__global__ __launch_bounds__(256) void k_sort(
    const int* __restrict__ out_idx, const int* __restrict__ in_idx,
    const int* __restrict__ rbase,
    int* __restrict__ offs, int* __restrict__ entries) {
    __shared__ int cnt[RSIZE];
    __shared__ unsigned list[CAP];
    __shared__ int psum[256];
    __shared__ int nlist;

    const int t = threadIdx.x;
    const int k = blockIdx.x / NRANGE;
    const int r = blockIdx.x % NRANGE;
    const int dlo = r * RSIZE;

    for (int i = t; i < RSIZE; i += 256) cnt[i] = 0;
    if (t == 0) nlist = 0;
    __syncthreads();

    const i32x4* dsrc = (const i32x4*)(out_idx + k * NPTS);
    const i32x4* ssrc = (const i32x4*)(in_idx + k * NPTS);
    for (int ii = t; ii < NPTS / 4; ii += 256) {
        i32x4 d4 = dsrc[ii];
        i32x4 s4 = ssrc[ii];
#pragma unroll
        for (int q = 0; q < 4; ++q) {
            unsigned dloc = (unsigned)(d4[q] - dlo);
            if (dloc < RSIZE) {
                atomicAdd(&cnt[dloc], 1);
                int p = atomicAdd(&nlist, 1);
                if (p < CAP) list[p] = (dloc << 17) | (unsigned)s4[q];
            }
        }
    }
    __syncthreads();

    const int T = (RSIZE + 255) / 256;    // 13
    int vals[T];
    int s = 0;
#pragma unroll
    for (int q = 0; q < T; ++q) {
        int i = t * T + q;
        int v = (i < RSIZE) ? cnt[i] : 0;
        vals[q] = v;
        s += v;
    }
    psum[t] = s;
    __syncthreads();
    for (int o = 1; o < 256; o <<= 1) {
        int pv = (t >= o) ? psum[t - o] : 0;
        __syncthreads();
        psum[t] += pv;
        __syncthreads();
    }
    int run = rbase[blockIdx.x] + (t ? psum[t - 1] : 0);
#pragma unroll
    for (int q = 0; q < T; ++q) {
        int i = t * T + q;
        if (i < RSIZE) {
            offs[k * NPTS + dlo + i] = run;
            cnt[i] = run;
            run += vals[q];
        }
    }
    __syncthreads();

    int nl = nlist < CAP ? nlist : CAP;
    for (int i = t; i < nl; i += 256) {
        unsigned u = list[i];
        int dloc = u >> 17;
        int src = u & 0x1FFFF;
        int p = atomicAdd(&cnt[dloc], 1);
        entries[p] = src;
    }
}

// ---------------- conv v2: rounds + direct-frag gather + depth-2 pipeline ----------------
__global__ __launch_bounds__(256, 3) void k_conv(
    const unsigned short* __restrict__ xb,    // [N][64] bf16
    const unsigned short* __restrict__ Wt,    // [27][cout=64][cin=64] bf16
    const int* __restrict__ offs,             // [SEGS+1], k-major
    const int* __restrict__ entries,          // [TOT] src indices
    float* __restrict__ y)                    // [N][64] fp32
{
    __shared__ __align__(16) unsigned short Bsh[2][CC * APAD];  // 18432 B
    __shared__ unsigned seginfo[KK * MT];                       // 13824 B: (gstart<<6)|cnt
    __shared__ int esh[2][MT];                                  // 1024 B: entry ring
    __shared__ int maxcnt[KK];

    const int tid  = threadIdx.x;
    const int lane = tid & 63;
    const int wave = tid >> 6;
    const int quad = lane >> 4;
    const int l16  = lane & 15;
    const int i0   = blockIdx.x * MT;

    // ---- prologue: seginfo + per-k max count ----
    if (tid < KK) maxcnt[tid] = 1;
    __syncthreads();
    for (int idx = tid; idx < KK * MT; idx += 256) {
        int k = idx >> 7;
        int r = idx & (MT - 1);
        int gi = i0 + r;
        unsigned pack = 0;
        int c = 0;
        if (gi < NPTS) {
            int seg = k * NPTS + gi;
            int b = offs[seg];
            c = offs[seg + 1] - b;
            c = c > 63 ? 63 : c;
            pack = ((unsigned)b << 6) | (unsigned)c;
        }
        seginfo[idx] = pack;
        atomicMax(&maxcnt[k], c);
    }
    // ---- B warm-up: Bsh[0] = Wt[0], prefetch Wt[1] ----
    const int bofs = tid * 16;
    const int brow = bofs >> 6, bcol = bofs & 63;
    u32x4 bw0 = ((const u32x4*)Wt)[tid * 2];
    u32x4 bw1 = ((const u32x4*)Wt)[tid * 2 + 1];
    *(u32x4*)&Bsh[0][brow * APAD + bcol]     = bw0;
    *(u32x4*)&Bsh[0][brow * APAD + bcol + 8] = bw1;
    bw0 = ((const u32x4*)(Wt + CC * CC))[tid * 2];
    bw1 = ((const u32x4*)(Wt + CC * CC))[tid * 2 + 1];
    __syncthreads();          // seginfo + maxcnt + Bsh[0] visible

    // ---- cursors ----
    int T = 0;
    for (int k = 0; k < KK; ++k) T += maxcnt[k];
    int ka = 0, ja = 0;                 // iter t
    int kb = 0, jb = 0;                 // iter t+1
    int kc = 0, jc = 0;                 // iter t+2
    {   // advance kb by 1, kc by 2
        jb++; if (jb >= maxcnt[kb]) { jb = 0; if (kb < KK - 1) kb++; }
        kc = kb; jc = jb;
        jc++; if (jc >= maxcnt[kc]) { jc = 0; if (kc < KK - 1) kc++; }
    }

    // ---- esh warm-up: entries for iter0 -> esh[0], iter1 -> esh[1] ----
    if (tid < MT) {
        unsigned s0 = seginfo[ka * MT + tid];
        unsigned s1 = seginfo[kb * MT + tid];
        int a0 = min((int)(s0 >> 6) + ja, TOT - 1);
        int a1 = min((int)(s1 >> 6) + jb, TOT - 1);
        esh[0][tid] = entries[a0];
        esh[1][tid] = entries[a1];
    }
    __syncthreads();

    // ---- cfrag warm-up for iter 0 ----
    const int row0 = wave * 32 + l16;       // mt = 0
    const int row1 = row0 + 16;             // mt = 1
    bf16x8 cfr[2][2];
    {
        bf16x8 z = {0,0,0,0,0,0,0,0};
        cfr[0][0] = z; cfr[0][1] = z; cfr[1][0] = z; cfr[1][1] = z;
        int e0 = esh[0][row0], e1 = esh[0][row1];
        unsigned sA = seginfo[ka * MT + row0];
        unsigned sB = seginfo[ka * MT + row1];
        if (ja < (int)(sA & 63)) {
            const unsigned short* p = xb + (long)e0 * CC + quad * 8;
            cfr[0][0] = *(const bf16x8*)p;
            cfr[0][1] = *(const bf16x8*)(p + 32);
        }
        if (ja < (int)(sB & 63)) {
            const unsigned short* p = xb + (long)e1 * CC + quad * 8;
            cfr[1][0] = *(const bf16x8*)p;
            cfr[1][1] = *(const bf16x8*)(p + 32);
        }
    }
    lds_barrier();   // protect esh[0] reads above from t=0's esh[0] rewrite

    f32x4 acc[2][4];
#pragma unroll
    for (int mt = 0; mt < 2; ++mt)
#pragma unroll
        for (int nt = 0; nt < 4; ++nt) acc[mt][nt] = (f32x4){0.f, 0.f, 0.f, 0.f};

    bf16x8 bfr[4][2];

    for (int t = 0; t < T; ++t) {
        // step1: issue entries load for iter t+2 (loader role)
        int er = 0;
        if (tid < MT) {
            unsigned sc = seginfo[kc * MT + tid];
            int ac = min((int)(sc >> 6) + jc, TOT - 1);
            er = entries[ac];
        }
        // step2: issue frag loads for iter t+1 from esh[(t+1)&1]
        bf16x8 nfr[2][2];
        {
            bf16x8 z = {0,0,0,0,0,0,0,0};
            nfr[0][0] = z; nfr[0][1] = z; nfr[1][0] = z; nfr[1][1] = z;
            int slot = (t + 1) & 1;
            int ne0 = esh[slot][row0], ne1 = esh[slot][row1];
            unsigned sb0 = seginfo[kb * MT + row0];
            unsigned sb1 = seginfo[kb * MT + row1];
            if (jb < (int)(sb0 & 63)) {
                const unsigned short* p = xb + (long)ne0 * CC + quad * 8;
                nfr[0][0] = *(const bf16x8*)p;
                nfr[0][1] = *(const bf16x8*)(p + 32);
            }
            if (jb < (int)(sb1 & 63)) {
                const unsigned short* p = xb + (long)ne1 * CC + quad * 8;
                nfr[1][0] = *(const bf16x8*)p;
                nfr[1][1] = *(const bf16x8*)(p + 32);
            }
        }
        // step3: B management (block-uniform branch, once per k)
        if (ja == 0) {
#pragma unroll
            for (int nt = 0; nt < 4; ++nt)
#pragma unroll
                for (int kt = 0; kt < 2; ++kt)
                    bfr[nt][kt] = *(const bf16x8*)&Bsh[ka & 1][(nt * 16 + l16) * APAD +
                                                              kt * 32 + quad * 8];
            // stage k+1's tile into the other buffer; prefetch k+2
            *(u32x4*)&Bsh[(ka + 1) & 1][brow * APAD + bcol]     = bw0;
            *(u32x4*)&Bsh[(ka + 1) & 1][brow * APAD + bcol + 8] = bw1;
            int kn = ka + 2 < KK ? ka + 2 : KK - 1;
            bw0 = ((const u32x4*)(Wt + kn * CC * CC))[tid * 2];
            bw1 = ((const u32x4*)(Wt + kn * CC * CC))[tid * 2 + 1];
        }
        // step4: MFMA for iter t
#pragma unroll
        for (int mt = 0; mt < 2; ++mt)
#pragma unroll
            for (int nt = 0; nt < 4; ++nt) {
                acc[mt][nt] = __builtin_amdgcn_mfma_f32_16x16x32_bf16(
                    cfr[mt][0], bfr[nt][0], acc[mt][nt], 0, 0, 0);
                acc[mt][nt] = __builtin_amdgcn_mfma_f32_16x16x32_bf16(
                    cfr[mt][1], bfr[nt][1], acc[mt][nt], 0, 0, 0);
            }
        // step5: loader commits entry for iter t+2 into slot (t+2)&1 == t&1
        if (tid < MT) esh[t & 1][tid] = er;
        // step6: rotate + advance
        cfr[0][0] = nfr[0][0]; cfr[0][1] = nfr[0][1];
        cfr[1][0] = nfr[1][0]; cfr[1][1] = nfr[1][1];
        ka = kb; ja = jb;
        kb = kc; jb = jc;
        jc++; if (jc >= maxcnt[kc]) { jc = 0; if (kc < KK - 1) kc++; }
        lds_barrier();
    }

    // epilogue: D row = quad*4 + r, col = l16 (within each 16x16 tile)
#pragma unroll
    for (int mt = 0; mt < 2; ++mt) {
        int rbase_ = i0 + wave * 32 + mt * 16 + quad * 4;
#pragma unroll
        for (int nt = 0; nt < 4; ++nt) {
            int col = nt * 16 + l16;
#pragma unroll
            for (int rr = 0; rr < 4; ++rr) {
                int gr = rbase_ + rr;
                if (gr < NPTS) y[(long)gr * CC + col] = acc[mt][nt][rr];
            }
        }
    }
}

// ---------------- BN ----------------
__global__ void k_bn_stats(const float* __restrict__ y, float* __restrict__ sums) {
    __shared__ float s1[256], s2[256];
    int t = threadIdx.x;
    int c = t & 63, g = t >> 6;
    float a = 0.f, b = 0.f;
    for (int i = blockIdx.x * 4 + g; i < NPTS; i += gridDim.x * 4) {
        float v = y[(long)i * CC + c];
        a += v; b += v * v;
    }
    s1[t] = a; s2[t] = b;
    __syncthreads();
    if (t < 64) {
        a = s1[t] + s1[t + 64] + s1[t + 128] + s1[t + 192];
        b = s2[t] + s2[t + 64] + s2[t + 128] + s2[t + 192];
        atomicAdd(&sums[t], a);
        atomicAdd(&sums[t + 64], b);
    }
}

__global__ void k_bn_fin(const float* __restrict__ sums, const float* __restrict__ gamma,
                         const float* __restrict__ beta, float* __restrict__ sb) {
    int c = threadIdx.x;   // 64 threads
    float mu  = sums[c] * (1.0f / NPTS);
    float var = sums[c + 64] * (1.0f / NPTS) - mu * mu;
    float s = gamma[c] * rsqrtf(var + EPSBN);
    sb[c] = s;
    sb[c + 64] = beta[c] - mu * s;
}

// a1 = bf16(relu(y*s + b))
__global__ void k_apply(const float* __restrict__ y, const float* __restrict__ sb,
                        unsigned short* __restrict__ ab) {
    int id = blockIdx.x * 256 + threadIdx.x;
    f32x4 v = ((const f32x4*)y)[id];
    int c0 = (id * 4) & 63;
    u16x4 o;
#pragma unroll
    for (int j = 0; j < 4; ++j) {
        float t = fmaxf(v[j] * sb[c0 + j] + sb[64 + c0 + j], 0.f);
        o[j] = f2bf(t);
    }
    ((u16x4*)ab)[id] = o;
}

// out = relu(y*s + b + x)
__global__ void k_final(const float* __restrict__ y, const float* __restrict__ x,
                        const float* __restrict__ sb, float* __restrict__ out) {
    int id = blockIdx.x * 256 + threadIdx.x;
    f32x4 v  = ((const f32x4*)y)[id];
    f32x4 xv = ((const f32x4*)x)[id];
    int c0 = (id * 4) & 63;
    f32x4 o;
#pragma unroll
    for (int j = 0; j < 4; ++j)
        o[j] = fmaxf(v[j] * sb[c0 + j] + sb[64 + c0 + j] + xv[j], 0.f);
    ((f32x4*)out)[id] = o;
}

extern "C" void kernel_launch(void* const* d_in, const int* in_sizes, int n_in,
                              void* d_out, int out_size, void* d_ws, size_t ws_size,
                              hipStream_t stream) {
    const float* x      = (const float*)d_in[0];
    // d_in[1] = norm_points (unused by the reference math)
    const float* W1     = (const float*)d_in[2];
    const float* gamma1 = (const float*)d_in[3];
    const float* beta1  = (const float*)d_in[4];
    const float* W2     = (const float*)d_in[5];
    const float* gamma2 = (const float*)d_in[6];
    const float* beta2  = (const float*)d_in[7];
    const int* in_idx   = (const int*)d_in[8];
    const int* out_idx  = (const int*)d_in[9];
    float* out = (float*)d_out;

    char* w = (char*)d_ws;
    size_t off = 0;
    auto alloc = [&](size_t bytes) -> char* {
        off = (off + 255) & ~(size_t)255;
        char* p = w + off;
        off += bytes;
        return p;
    };
    int*   rcnt    = (int*)  alloc((size_t)KK * NRANGE * 4);
    float* sums    = (float*)alloc(256 * 4);            // [0:128) layer1, [128:256) layer2
    int*   rbase   = (int*)  alloc((size_t)KK * NRANGE * 4);
    float* sb      = (float*)alloc(256 * 4);
    int*   offs    = (int*)  alloc(((size_t)SEGS + 1) * 4);
    int*   entries = (int*)  alloc((size_t)SEGS * 4);
    unsigned short* xbf = (unsigned short*)alloc((size_t)NPTS * CC * 2);
    unsigned short* Wt1 = (unsigned short*)alloc((size_t)KK * CC * CC * 2);
    unsigned short* Wt2 = (unsigned short*)alloc((size_t)KK * CC * CC * 2);
    float* y = (float*)alloc((size_t)NPTS * CC * 4);

    // zero rcnt + sums (contiguous; covers alignment gap)
    size_t zlen = (size_t)((char*)(sums + 256) - (char*)rcnt);
    hipMemsetAsync(rcnt, 0, zlen, stream);

    k_convert_x<<<NPTS * CC / 1024, 256, 0, stream>>>(x, xbf);
    k_prep_w<<<(2 * KK * CC * CC) / 256, 256, 0, stream>>>(W1, W2, Wt1, Wt2);
    k_rhist<<<TOT / CHUNK, 256, 0, stream>>>(out_idx, rcnt);
    k_rscan<<<1, 64, 0, stream>>>(rcnt, rbase, offs);
    k_sort<<<KK * NRANGE, 256, 0, stream>>>(out_idx, in_idx, rbase, offs, entries);

    const int CONVB = (NPTS + MT - 1) / MT;
    k_conv<<<CONVB, 256, 0, stream>>>(xbf, Wt1, offs, entries, y);
    k_bn_stats<<<256, 256, 0, stream>>>(y, sums);
    k_bn_fin<<<1, 64, 0, stream>>>(sums, gamma1, beta1, sb);
    k_apply<<<NPTS * CC / 1024, 256, 0, stream>>>(y, sb, xbf);   // a1 overwrites xbf
    k_conv<<<CONVB, 256, 0, stream>>>(xbf, Wt2, offs, entries, y);
    k_bn_stats<<<256, 256, 0, stream>>>(y, sums + 128);
    k_bn_fin<<<1, 64, 0, stream>>>(sums + 128, gamma2, beta2, sb + 128);
    k_final<<<NPTS * CC / 1024, 256, 0, stream>>>(y, x, sb + 128, out);
}